// Round 2
// baseline (468.515 us; speedup 1.0000x reference)
//
#include <hip/hip_runtime.h>
#include <hip/hip_cooperative_groups.h>
#include <stdint.h>

namespace cg = cooperative_groups;

// RelationalMSG, single cooperative mega-kernel (7 phases, 6 grid.sync):
//   P0: zero hist + convert W1/W2 -> MFMA B-fragment layout (bf16)
//   P1: gemm1  Ys = x@W1a, Yd = x@W1b + b1  (x converted in-reg)  ||  edge histogram
//   P2: per-1024-chunk exclusive scan of hist (block-local)
//   P3: cross-chunk offsets -> rowptr, cursor
//   P4: counting-sort scatter of edge src by dst (atomic cursor)
//   P5: CSR aggregation  agg[n] = sum_e relu(Ys[src_e] + Yd[n])   (no atomics)
//   P6: gemm2  out = x + relu([x;agg]@W2 + b2)  (x converted in-reg; xb eliminated)
// N=50000 (16 | N), E=600000, D=128.

typedef __attribute__((ext_vector_type(8))) short short8;   // 8 bf16 (MFMA A/B frag)
typedef __attribute__((ext_vector_type(4))) float floatx4;  // MFMA C/D frag

#define D 128

static __device__ __forceinline__ unsigned short f2bf(float f) {
    union { float f; unsigned int u; } v; v.f = f;
    unsigned int r = (v.u + 0x7fffu + ((v.u >> 16) & 1u)) >> 16; // RNE
    return (unsigned short)r;
}
static __device__ __forceinline__ float bflo(unsigned int u) {
    union { unsigned int u; float f; } v; v.u = u << 16; return v.f;
}
static __device__ __forceinline__ float bfhi(unsigned int u) {
    union { unsigned int u; float f; } v; v.u = u & 0xffff0000u; return v.f;
}

// B-fragment layouts (column-PERMUTED so each lane's frags hold ADJACENT output cols):
// w1f (gemm1, K=128, 256 out cols): frag[(kk*16+ct)*64+lane][j] =
//      B1[kk*32+(lane>>4)*8+j][ (ct>>2)*64 + 4*(lane&15) + (ct&3) ]
//   B1[k][c] = c<128 ? W1[k][c] : W1[128+k][c-128]   (W1 is [256][128])
// w2f (gemm2, K=256, 128 out cols): frag[(kk*8+ct)*64+lane][j] =
//      W2[kk*32+(lane>>4)*8+j][ (ct>>1)*32 + 2*(lane&15) + (ct&1) ]

__global__ __launch_bounds__(256) void k_mega(
    const float* __restrict__ x,
    const int* __restrict__ esrc,
    const int* __restrict__ edst,
    const float* __restrict__ W1,
    const float* __restrict__ b1,
    const float* __restrict__ W2,
    const float* __restrict__ b2,
    float* __restrict__ out,
    unsigned short* __restrict__ w1f,
    unsigned short* __restrict__ w2f,
    unsigned short* __restrict__ Ys,
    unsigned short* __restrict__ Yd,
    unsigned short* __restrict__ aggb,
    int* __restrict__ cnt,
    int* __restrict__ rowptr,
    int* __restrict__ cursor,
    int* __restrict__ bsum,
    int* __restrict__ ssrc,
    int N, int E, int nTiles)
{
    cg::grid_group grid = cg::this_grid();
    const int G  = gridDim.x;
    const int GT = G * 256;
    const int tid = threadIdx.x;
    const int gid0 = blockIdx.x * 256 + tid;
    const int w = tid >> 6, lane = tid & 63;
    const int quad = lane >> 4, col = lane & 15;
    __shared__ int sh[9];

    // ---------------- P0: zero hist + weight conversion ----------------
    for (int i = gid0; i < N; i += GT) cnt[i] = 0;
    for (int g = gid0; g < 65536; g += GT) {
        if (g < 32768) {
            int j = g & 7, l = (g >> 3) & 63, ct = (g >> 9) & 15, kk = g >> 13;
            int k = kk * 32 + (l >> 4) * 8 + j;
            int c = ((ct >> 2) << 6) + ((l & 15) << 2) + (ct & 3);
            float v = (c < 128) ? W1[k * 128 + c] : W1[(128 + k) * 128 + (c - 128)];
            w1f[g] = f2bf(v);
        } else {
            int t2 = g - 32768;
            int j = t2 & 7, l = (t2 >> 3) & 63, ct = (t2 >> 9) & 7, kk = t2 >> 12;
            int k = kk * 32 + (l >> 4) * 8 + j;
            int c = ((ct >> 1) << 5) + ((l & 15) << 1) + (ct & 1);
            w2f[t2] = f2bf(W2[k * 128 + c]);
        }
    }
    grid.sync();

    // ---------------- P1: gemm1 || edge histogram ----------------
    {
        short8 wf[4][4];
#pragma unroll
        for (int kk = 0; kk < 4; kk++)
#pragma unroll
            for (int j = 0; j < 4; j++)
                wf[kk][j] = ((const short8*)w1f)[(kk * 16 + w * 4 + j) * 64 + lane];
        float4 bias = make_float4(0.f, 0.f, 0.f, 0.f);
        if (w >= 2) bias = *(const float4*)(b1 + (w - 2) * 64 + col * 4);
        unsigned short* Yhalf = (w < 2) ? Ys : Yd;
        const int cb = (w & 1) * 64;

        for (int t = blockIdx.x; t < nTiles; t += G) {
            const int n0 = t * 16;
            const int nr = n0 + col;                 // N % 16 == 0
            const float* xrow = x + (long)nr * D;
            floatx4 acc[4];
#pragma unroll
            for (int j = 0; j < 4; j++)
#pragma unroll
                for (int q = 0; q < 4; q++) acc[j][q] = 0.f;
#pragma unroll
            for (int kk = 0; kk < 4; kk++) {
                float4 f0 = *(const float4*)(xrow + kk * 32 + quad * 8);
                float4 f1 = *(const float4*)(xrow + kk * 32 + quad * 8 + 4);
                union { short8 s; unsigned int u[4]; } au;
                asm("v_cvt_pk_bf16_f32 %0, %1, %2" : "=v"(au.u[0]) : "v"(f0.x), "v"(f0.y));
                asm("v_cvt_pk_bf16_f32 %0, %1, %2" : "=v"(au.u[1]) : "v"(f0.z), "v"(f0.w));
                asm("v_cvt_pk_bf16_f32 %0, %1, %2" : "=v"(au.u[2]) : "v"(f1.x), "v"(f1.y));
                asm("v_cvt_pk_bf16_f32 %0, %1, %2" : "=v"(au.u[3]) : "v"(f1.z), "v"(f1.w));
#pragma unroll
                for (int j = 0; j < 4; j++)
                    acc[j] = __builtin_amdgcn_mfma_f32_16x16x32_bf16(au.s, wf[kk][j], acc[j], 0, 0, 0);
            }
#pragma unroll
            for (int r = 0; r < 4; r++) {
                int n = n0 + quad * 4 + r;
                ushort4 o;
                o.x = f2bf(acc[0][r] + bias.x);
                o.y = f2bf(acc[1][r] + bias.y);
                o.z = f2bf(acc[2][r] + bias.z);
                o.w = f2bf(acc[3][r] + bias.w);
                *(ushort4*)(Yhalf + (long)n * D + cb + col * 4) = o;
            }
        }
    }
    for (int i = gid0; i < E; i += GT) atomicAdd(&cnt[edst[i]], 1);
    grid.sync();

    // ---------------- P2: block-local exclusive scan (1024-node chunks) ----------------
    {
        const int nbChunks = (N + 1023) >> 10;
        for (int b = blockIdx.x; b < nbChunks; b += G) {
            int i0 = (b << 10) + tid * 4;
            int v0 = 0, v1 = 0, v2 = 0, v3 = 0;
            if (i0 + 3 < N) {
                int4 c4 = *(const int4*)(cnt + i0);
                v0 = c4.x; v1 = c4.y; v2 = c4.z; v3 = c4.w;
            } else {
                if (i0     < N) v0 = cnt[i0];
                if (i0 + 1 < N) v1 = cnt[i0 + 1];
                if (i0 + 2 < N) v2 = cnt[i0 + 2];
                if (i0 + 3 < N) v3 = cnt[i0 + 3];
            }
            int s1 = v0 + v1, s2 = s1 + v2, S = s2 + v3;
            int incl = S;
#pragma unroll
            for (int off = 1; off < 64; off <<= 1) {
                int tt = __shfl_up(incl, off, 64);
                if (lane >= off) incl += tt;
            }
            if (lane == 63) sh[w] = incl;
            __syncthreads();
            if (tid == 0) {
                int a0 = sh[0], a1 = sh[1], a2 = sh[2], a3 = sh[3];
                sh[0] = 0; sh[1] = a0; sh[2] = a0 + a1; sh[3] = a0 + a1 + a2;
                sh[4] = a0 + a1 + a2 + a3;
            }
            __syncthreads();
            int texcl = incl - S + sh[w];
            if (i0 + 3 < N) {
                *(int4*)(rowptr + i0) = make_int4(texcl, texcl + v0, texcl + s1, texcl + s2);
            } else {
                if (i0     < N) rowptr[i0]     = texcl;
                if (i0 + 1 < N) rowptr[i0 + 1] = texcl + v0;
                if (i0 + 2 < N) rowptr[i0 + 2] = texcl + s1;
                if (i0 + 3 < N) rowptr[i0 + 3] = texcl + s2;
            }
            if (tid == 0) bsum[b] = sh[4];
            __syncthreads();
        }
    }
    grid.sync();

    // ---------------- P3: add cross-chunk offsets -> rowptr, cursor ----------------
    for (long ib = (long)blockIdx.x * 256; ib < N; ib += GT) {
        int chunk = (int)(ib >> 10);   // uniform per block per iteration
        if (tid < 64) {
            int v = (tid < chunk) ? bsum[tid] : 0;
#pragma unroll
            for (int off = 32; off; off >>= 1) v += __shfl_down(v, off, 64);
            if (tid == 0) sh[8] = v;
        }
        __syncthreads();
        int i = (int)ib + tid;
        if (i < N) {
            int r = rowptr[i] + sh[8];
            rowptr[i] = r;
            cursor[i] = r;
        }
        __syncthreads();
    }
    if (gid0 == 0) rowptr[N] = E;
    grid.sync();

    // ---------------- P4: counting-sort scatter ----------------
    for (int i = gid0; i < E; i += GT) {
        int p = atomicAdd(&cursor[edst[i]], 1);
        ssrc[p] = esrc[i];
    }
    grid.sync();

    // ---------------- P5: CSR aggregation (one wave per dst node) ----------------
    for (int wv = blockIdx.x * 4 + w; wv < N; wv += G * 4) {
        int rp0 = rowptr[wv], rp1 = rowptr[wv + 1];
        unsigned int ydu = *(const unsigned int*)(Yd + (long)wv * D + lane * 2);
        float yd0 = bflo(ydu), yd1 = bfhi(ydu);
        float a0 = 0.f, a1 = 0.f;
        const unsigned short* ysl = Ys + lane * 2;
        int e = rp0;
        for (; e + 8 <= rp1; e += 8) {
            int s[8]; unsigned int u[8];
#pragma unroll
            for (int q = 0; q < 8; q++) s[q] = ssrc[e + q];
#pragma unroll
            for (int q = 0; q < 8; q++) u[q] = *(const unsigned int*)(ysl + (long)s[q] * D);
#pragma unroll
            for (int q = 0; q < 8; q++) {
                a0 += fmaxf(bflo(u[q]) + yd0, 0.f);
                a1 += fmaxf(bfhi(u[q]) + yd1, 0.f);
            }
        }
        for (; e + 4 <= rp1; e += 4) {
            int s[4]; unsigned int u[4];
#pragma unroll
            for (int q = 0; q < 4; q++) s[q] = ssrc[e + q];
#pragma unroll
            for (int q = 0; q < 4; q++) u[q] = *(const unsigned int*)(ysl + (long)s[q] * D);
#pragma unroll
            for (int q = 0; q < 4; q++) {
                a0 += fmaxf(bflo(u[q]) + yd0, 0.f);
                a1 += fmaxf(bfhi(u[q]) + yd1, 0.f);
            }
        }
        for (; e < rp1; e++) {
            unsigned int u0 = *(const unsigned int*)(ysl + (long)ssrc[e] * D);
            a0 += fmaxf(bflo(u0) + yd0, 0.f);
            a1 += fmaxf(bfhi(u0) + yd1, 0.f);
        }
        unsigned int o = (unsigned int)f2bf(a0) | ((unsigned int)f2bf(a1) << 16);
        *(unsigned int*)(aggb + (long)wv * D + lane * 2) = o;
    }
    grid.sync();

    // ---------------- P6: gemm2 (A from x in-reg + aggb), residual epilogue ----------------
    {
        short8 wf2[8][2];
#pragma unroll
        for (int kk = 0; kk < 8; kk++)
#pragma unroll
            for (int c = 0; c < 2; c++)
                wf2[kk][c] = ((const short8*)w2f)[(kk * 8 + w * 2 + c) * 64 + lane];
        float2 bias2 = *(const float2*)(b2 + w * 32 + col * 2);

        for (int t = blockIdx.x; t < nTiles; t += G) {
            const int n0 = t * 16;
            const int nr = n0 + col;                 // N % 16 == 0
            const float* xrow = x + (long)nr * D;
            floatx4 acc[2];
#pragma unroll
            for (int c = 0; c < 2; c++)
#pragma unroll
                for (int q = 0; q < 4; q++) acc[c][q] = 0.f;
#pragma unroll
            for (int kk = 0; kk < 4; kk++) {
                float4 f0 = *(const float4*)(xrow + kk * 32 + quad * 8);
                float4 f1 = *(const float4*)(xrow + kk * 32 + quad * 8 + 4);
                union { short8 s; unsigned int u[4]; } au;
                asm("v_cvt_pk_bf16_f32 %0, %1, %2" : "=v"(au.u[0]) : "v"(f0.x), "v"(f0.y));
                asm("v_cvt_pk_bf16_f32 %0, %1, %2" : "=v"(au.u[1]) : "v"(f0.z), "v"(f0.w));
                asm("v_cvt_pk_bf16_f32 %0, %1, %2" : "=v"(au.u[2]) : "v"(f1.x), "v"(f1.y));
                asm("v_cvt_pk_bf16_f32 %0, %1, %2" : "=v"(au.u[3]) : "v"(f1.z), "v"(f1.w));
                acc[0] = __builtin_amdgcn_mfma_f32_16x16x32_bf16(au.s, wf2[kk][0], acc[0], 0, 0, 0);
                acc[1] = __builtin_amdgcn_mfma_f32_16x16x32_bf16(au.s, wf2[kk][1], acc[1], 0, 0, 0);
            }
#pragma unroll
            for (int kk = 4; kk < 8; kk++) {
                short8 a = *(const short8*)(aggb + (long)nr * D + (kk - 4) * 32 + quad * 8);
                acc[0] = __builtin_amdgcn_mfma_f32_16x16x32_bf16(a, wf2[kk][0], acc[0], 0, 0, 0);
                acc[1] = __builtin_amdgcn_mfma_f32_16x16x32_bf16(a, wf2[kk][1], acc[1], 0, 0, 0);
            }
#pragma unroll
            for (int r = 0; r < 4; r++) {
                int n = n0 + quad * 4 + r;
                long off = (long)n * D + w * 32 + col * 2;
                float2 xr = *(const float2*)(x + off);
                float v0 = fmaxf(acc[0][r] + bias2.x, 0.f);
                float v1 = fmaxf(acc[1][r] + bias2.y, 0.f);
                *(float2*)(out + off) = make_float2(xr.x + v0, xr.y + v1);
            }
        }
    }
}

extern "C" void kernel_launch(void* const* d_in, const int* in_sizes, int n_in,
                              void* d_out, int out_size, void* d_ws, size_t ws_size,
                              hipStream_t stream)
{
    const float* x   = (const float*)d_in[0];
    const int* esrc  = (const int*)d_in[1];
    const int* edst  = (const int*)d_in[2];
    const float* W1  = (const float*)d_in[3];
    const float* b1  = (const float*)d_in[4];
    const float* W2  = (const float*)d_in[5];
    const float* b2  = (const float*)d_in[6];
    float* out = (float*)d_out;

    const int ND = in_sizes[0];     // N*D
    int N = ND / D;                 // 50000
    int E = in_sizes[1];            // 600000

    // workspace carve-out (256B-aligned chunks), ~42 MB
    char* p = (char*)d_ws;
    auto alloc = [&](size_t bytes) { char* r = p; p += (bytes + 255) & ~(size_t)255; return r; };
    unsigned short* Ys   = (unsigned short*)alloc((size_t)ND * 2);
    unsigned short* Yd   = (unsigned short*)alloc((size_t)ND * 2);
    unsigned short* aggb = (unsigned short*)alloc((size_t)ND * 2);
    unsigned short* w1f  = (unsigned short*)alloc(32768 * 2);
    unsigned short* w2f  = (unsigned short*)alloc(32768 * 2);
    int* rowptr = (int*)alloc((size_t)(N + 1) * 4);
    int* cursor = (int*)alloc((size_t)N * 4);
    int* cnt    = (int*)alloc((size_t)N * 4);
    int* bsum   = (int*)alloc(64 * 4);
    int* ssrc   = (int*)alloc((size_t)E * 4);

    int nTiles = N / 16;            // 3125 (N % 16 == 0)

    // Cooperative grid size: full co-residency guaranteed by occupancy query.
    static int G = 0;
    if (G == 0) {
        int nb = 0;
        hipError_t e1 = hipOccupancyMaxActiveBlocksPerMultiprocessor(&nb, k_mega, 256, 0);
        int cus = 256;
        hipDeviceProp_t prop;
        if (hipGetDeviceProperties(&prop, 0) == hipSuccess && prop.multiProcessorCount > 0)
            cus = prop.multiProcessorCount;
        long g = (e1 == hipSuccess && nb > 0) ? (long)nb * cus : 256;
        if (g > 1536) g = 1536;
        if (g < 64)  g = 64;
        G = (int)g;
    }

    void* args[] = {
        (void*)&x, (void*)&esrc, (void*)&edst, (void*)&W1, (void*)&b1,
        (void*)&W2, (void*)&b2, (void*)&out, (void*)&w1f, (void*)&w2f,
        (void*)&Ys, (void*)&Yd, (void*)&aggb, (void*)&cnt, (void*)&rowptr,
        (void*)&cursor, (void*)&bsum, (void*)&ssrc,
        (void*)&N, (void*)&E, (void*)&nTiles
    };
    hipLaunchCooperativeKernel(k_mega, dim3(G), dim3(256), args, 0, stream);
}

// Round 3
// 245.884 us; speedup vs baseline: 1.9054x; 1.9054x over previous
//
#include <hip/hip_runtime.h>
#include <stdint.h>

// RelationalMSG decomposed, 6 dispatches (no grid.sync — it cost ~50us/barrier on 8 XCDs):
//   D1 k_pre:    zero hist + convert W1/W2 -> MFMA B-fragment layout (bf16)
//   D2 k_fat1:   block-partitioned: gemm1 (Ys = x@W1a, Yd = x@W1b + b1, x cvt in-reg)
//                                   || edge histogram (independent work, same dispatch)
//   D3 k_scan:   single-block 2-pass exclusive scan of cnt -> rowptr, cursor
//   D4 k_scatter: counting-sort scatter of edge src by dst
//   D5 k_agg:    CSR aggregation agg[n] = sum_e relu(Ys[src_e] + Yd[n])  (no atomics)
//   D6 k_gemm2:  out = x + relu([x;agg]@W2 + b2)  (x cvt in-reg; xb buffer eliminated)
// N=50000 (16 | N), E=600000, D=128.

typedef __attribute__((ext_vector_type(8))) short short8;   // 8 bf16 (MFMA A/B frag)
typedef __attribute__((ext_vector_type(4))) float floatx4;  // MFMA C/D frag

#define D 128

static __device__ __forceinline__ unsigned short f2bf(float f) {
    union { float f; unsigned int u; } v; v.f = f;
    unsigned int r = (v.u + 0x7fffu + ((v.u >> 16) & 1u)) >> 16; // RNE
    return (unsigned short)r;
}
static __device__ __forceinline__ float bflo(unsigned int u) {
    union { unsigned int u; float f; } v; v.u = u << 16; return v.f;
}
static __device__ __forceinline__ float bfhi(unsigned int u) {
    union { unsigned int u; float f; } v; v.u = u & 0xffff0000u; return v.f;
}

// B-fragment layouts (column-PERMUTED so each lane's frags hold ADJACENT output cols):
// w1f (gemm1, K=128, 256 out cols): frag[(kk*16+ct)*64+lane][j] =
//      B1[kk*32+(lane>>4)*8+j][ (ct>>2)*64 + 4*(lane&15) + (ct&3) ]
//   B1[k][c] = c<128 ? W1[k][c] : W1[128+k][c-128]   (W1 is [256][128])
// w2f (gemm2, K=256, 128 out cols): frag[(kk*8+ct)*64+lane][j] =
//      W2[kk*32+(lane>>4)*8+j][ (ct>>1)*32 + 2*(lane&15) + (ct&1) ]
__global__ void k_pre(const float* __restrict__ W1, const float* __restrict__ W2,
                      unsigned short* __restrict__ w1f, unsigned short* __restrict__ w2f,
                      int* __restrict__ cnt, int N) {
    int gid = blockIdx.x * blockDim.x + threadIdx.x; // 65536 threads
    if (gid < N) cnt[gid] = 0;
    if (gid < 32768) {
        int tid = gid;
        int j = tid & 7, lane = (tid >> 3) & 63, ct = (tid >> 9) & 15, kk = tid >> 13;
        int k = kk * 32 + (lane >> 4) * 8 + j;
        int c = ((ct >> 2) << 6) + ((lane & 15) << 2) + (ct & 3);
        float v = (c < 128) ? W1[k * 128 + c] : W1[(128 + k) * 128 + (c - 128)];
        w1f[tid] = f2bf(v);
    } else {
        int tid = gid - 32768;
        int j = tid & 7, lane = (tid >> 3) & 63, ct = (tid >> 9) & 7, kk = tid >> 12;
        int k = kk * 32 + (lane >> 4) * 8 + j;
        int c = ((ct >> 1) << 5) + ((lane & 15) << 1) + (ct & 1);
        w2f[tid] = f2bf(W2[k * 128 + c]);
    }
}

// D2: blocks [0,nb1) = gemm1; blocks [nb1,grid) = edge histogram. Independent work,
// co-scheduled in one dispatch so hist hides under gemm1.
// gemm1: M=N, K=128, Nout=256. Block = 4 waves; wave w owns out-cols [w*64, w*64+64).
// Frag j of wave w holds actual col w*64 + 4*(lane&15) + j  ->  8B ushort4 stores.
__global__ __launch_bounds__(256) void k_fat1(
    const float* __restrict__ x,
    const unsigned short* __restrict__ w1f,
    const float* __restrict__ b1,
    unsigned short* __restrict__ Ys,
    unsigned short* __restrict__ Yd,
    const int* __restrict__ edst,
    int* __restrict__ cnt,
    int N, int nTiles, int nb1, int E)
{
    const int tid = threadIdx.x;
    if ((int)blockIdx.x >= nb1) {
        // ---- histogram part ----
        const int hthreads = (gridDim.x - nb1) * 256;
        const int hid = (blockIdx.x - nb1) * 256 + tid;
        const int E4 = E >> 2;
        for (int i = hid; i < E4; i += hthreads) {
            int4 d = ((const int4*)edst)[i];
            atomicAdd(&cnt[d.x], 1);
            atomicAdd(&cnt[d.y], 1);
            atomicAdd(&cnt[d.z], 1);
            atomicAdd(&cnt[d.w], 1);
        }
        for (int i = (E4 << 2) + hid; i < E; i += hthreads)
            atomicAdd(&cnt[edst[i]], 1);
        return;
    }
    // ---- gemm1 part ----
    const int w = tid >> 6, lane = tid & 63;
    const int quad = lane >> 4, col = lane & 15;

    short8 wf[4][4];
#pragma unroll
    for (int kk = 0; kk < 4; kk++)
#pragma unroll
        for (int j = 0; j < 4; j++)
            wf[kk][j] = ((const short8*)w1f)[(kk * 16 + w * 4 + j) * 64 + lane];
    float4 bias = make_float4(0.f, 0.f, 0.f, 0.f);
    if (w >= 2) bias = *(const float4*)(b1 + (w - 2) * 64 + col * 4);
    unsigned short* Yhalf = (w < 2) ? Ys : Yd;
    const int cb = (w & 1) * 64;

    for (int t = blockIdx.x; t < nTiles; t += nb1) {
        const int n0 = t * 16;
        const int nr = n0 + col;                 // N % 16 == 0
        const float* xrow = x + (long)nr * D;
        floatx4 acc[4];
#pragma unroll
        for (int j = 0; j < 4; j++)
#pragma unroll
            for (int q = 0; q < 4; q++) acc[j][q] = 0.f;
#pragma unroll
        for (int kk = 0; kk < 4; kk++) {
            float4 f0 = *(const float4*)(xrow + kk * 32 + quad * 8);
            float4 f1 = *(const float4*)(xrow + kk * 32 + quad * 8 + 4);
            union { short8 s; unsigned int u[4]; } au;
            asm("v_cvt_pk_bf16_f32 %0, %1, %2" : "=v"(au.u[0]) : "v"(f0.x), "v"(f0.y));
            asm("v_cvt_pk_bf16_f32 %0, %1, %2" : "=v"(au.u[1]) : "v"(f0.z), "v"(f0.w));
            asm("v_cvt_pk_bf16_f32 %0, %1, %2" : "=v"(au.u[2]) : "v"(f1.x), "v"(f1.y));
            asm("v_cvt_pk_bf16_f32 %0, %1, %2" : "=v"(au.u[3]) : "v"(f1.z), "v"(f1.w));
#pragma unroll
            for (int j = 0; j < 4; j++)
                acc[j] = __builtin_amdgcn_mfma_f32_16x16x32_bf16(au.s, wf[kk][j], acc[j], 0, 0, 0);
        }
#pragma unroll
        for (int r = 0; r < 4; r++) {
            int n = n0 + quad * 4 + r;
            ushort4 o;
            o.x = f2bf(acc[0][r] + bias.x);
            o.y = f2bf(acc[1][r] + bias.y);
            o.z = f2bf(acc[2][r] + bias.z);
            o.w = f2bf(acc[3][r] + bias.w);
            *(ushort4*)(Yhalf + (long)n * D + cb + col * 4) = o;
        }
    }
}

// D3: single-block 2-pass scan. 1024 threads, 52 elems each (13 x int4), shfl+LDS
// hierarchy, writes rowptr and cursor. cnt is L2-hot (just written by hist).
__global__ __launch_bounds__(1024) void k_scan(const int* __restrict__ cnt,
                                               int* __restrict__ rowptr,
                                               int* __restrict__ cursor, int N, int E) {
    __shared__ int ws[16];
    const int tid = threadIdx.x, lane = tid & 63, wv = tid >> 6;
    const int base = tid * 52;
    // pass 1: per-thread sum
    int sum = 0;
#pragma unroll
    for (int q = 0; q < 13; q++) {
        int i = base + q * 4;
        if (i + 3 < N) {
            int4 c = *(const int4*)(cnt + i);
            sum += c.x + c.y + c.z + c.w;
        } else {
#pragma unroll
            for (int r = 0; r < 4; r++) if (i + r < N) sum += cnt[i + r];
        }
    }
    int incl = sum;
#pragma unroll
    for (int off = 1; off < 64; off <<= 1) {
        int t = __shfl_up(incl, off, 64);
        if (lane >= off) incl += t;
    }
    if (lane == 63) ws[wv] = incl;
    __syncthreads();
    if (wv == 0) {
        int v = (lane < 16) ? ws[lane] : 0;
        int s = v;
#pragma unroll
        for (int off = 1; off < 16; off <<= 1) {
            int t = __shfl_up(s, off, 64);
            if (lane >= off) s += t;
        }
        if (lane < 16) ws[lane] = s - v;   // exclusive wave offsets
    }
    __syncthreads();
    int run = incl - sum + ws[wv];          // exclusive prefix for this thread's chunk
    // pass 2: write exclusive scan
#pragma unroll
    for (int q = 0; q < 13; q++) {
        int i = base + q * 4;
        if (i + 3 < N) {
            int4 c = *(const int4*)(cnt + i);
            int4 o = make_int4(run, run + c.x, run + c.x + c.y, run + c.x + c.y + c.z);
            *(int4*)(rowptr + i) = o;
            *(int4*)(cursor + i) = o;
            run += c.x + c.y + c.z + c.w;
        } else {
#pragma unroll
            for (int r = 0; r < 4; r++)
                if (i + r < N) { rowptr[i + r] = run; cursor[i + r] = run; run += cnt[i + r]; }
        }
    }
    if (tid == 0) rowptr[N] = E;
}

// D4: counting-sort scatter (vectorized edge reads).
__global__ void k_scatter(const int* __restrict__ src, const int* __restrict__ dst,
                          int* __restrict__ cursor, int* __restrict__ ssrc, int E) {
    int i = blockIdx.x * blockDim.x + threadIdx.x;
    const int E4 = E >> 2;
    if (i < E4) {
        int4 s = ((const int4*)src)[i];
        int4 d = ((const int4*)dst)[i];
        int p0 = atomicAdd(&cursor[d.x], 1); ssrc[p0] = s.x;
        int p1 = atomicAdd(&cursor[d.y], 1); ssrc[p1] = s.y;
        int p2 = atomicAdd(&cursor[d.z], 1); ssrc[p2] = s.z;
        int p3 = atomicAdd(&cursor[d.w], 1); ssrc[p3] = s.w;
    }
    if (i < (E & 3)) {
        int e = (E4 << 2) + i;
        int p = atomicAdd(&cursor[dst[e]], 1);
        ssrc[p] = src[e];
    }
}

// D5: CSR aggregation: one wave per dst node. agg[n] = sum_e relu(Ys[src_e] + Yd[n]).
// Lane handles 2 of 128 cols (bf16x2). 8-deep: 8 independent 256B row reads in flight.
__global__ __launch_bounds__(256) void k_agg(
    const unsigned short* __restrict__ Ys,
    const unsigned short* __restrict__ Yd,
    const int* __restrict__ rowptr,
    const int* __restrict__ ssrc,
    unsigned short* __restrict__ aggb, int N)
{
    int wv = blockIdx.x * 4 + (threadIdx.x >> 6);
    if (wv >= N) return;
    int lane = threadIdx.x & 63;
    int rp0 = rowptr[wv], rp1 = rowptr[wv + 1];
    unsigned int ydu = *(const unsigned int*)(Yd + (long)wv * D + lane * 2);
    float yd0 = bflo(ydu), yd1 = bfhi(ydu);
    float a0 = 0.f, a1 = 0.f;
    const unsigned short* ysl = Ys + lane * 2;
    int e = rp0;
    for (; e + 8 <= rp1; e += 8) {
        int s[8]; unsigned int u[8];
#pragma unroll
        for (int q = 0; q < 8; q++) s[q] = ssrc[e + q];
#pragma unroll
        for (int q = 0; q < 8; q++) u[q] = *(const unsigned int*)(ysl + (long)s[q] * D);
#pragma unroll
        for (int q = 0; q < 8; q++) {
            a0 += fmaxf(bflo(u[q]) + yd0, 0.f);
            a1 += fmaxf(bfhi(u[q]) + yd1, 0.f);
        }
    }
    for (; e + 4 <= rp1; e += 4) {
        int s[4]; unsigned int u[4];
#pragma unroll
        for (int q = 0; q < 4; q++) s[q] = ssrc[e + q];
#pragma unroll
        for (int q = 0; q < 4; q++) u[q] = *(const unsigned int*)(ysl + (long)s[q] * D);
#pragma unroll
        for (int q = 0; q < 4; q++) {
            a0 += fmaxf(bflo(u[q]) + yd0, 0.f);
            a1 += fmaxf(bfhi(u[q]) + yd1, 0.f);
        }
    }
    for (; e < rp1; e++) {
        unsigned int u0 = *(const unsigned int*)(ysl + (long)ssrc[e] * D);
        a0 += fmaxf(bflo(u0) + yd0, 0.f);
        a1 += fmaxf(bfhi(u0) + yd1, 0.f);
    }
    unsigned int o = (unsigned int)f2bf(a0) | ((unsigned int)f2bf(a1) << 16);
    *(unsigned int*)(aggb + (long)wv * D + lane * 2) = o;
}

// D6: out = x + relu([x;agg]@W2 + b2). M=N, K=256, Nout=128. A-operand for K<128
// converted from fp32 x in-register (xb buffer eliminated; x rows are L2-hot from
// the residual read). Block = 4 waves; wave w owns out-cols [w*32, w*32+32).
// Frag c of wave w holds actual col w*32 + 2*(lane&15) + c  ->  8B float2 stores.
__global__ __launch_bounds__(256) void k_gemm2(
    const float* __restrict__ x,
    const unsigned short* __restrict__ aggb,
    const unsigned short* __restrict__ w2f,
    const float* __restrict__ b2,
    float* __restrict__ out,
    int N, int nTiles, int nb2)
{
    const int tid = threadIdx.x, w = tid >> 6, lane = tid & 63;
    const int quad = lane >> 4, col = lane & 15;

    short8 wf[8][2];
#pragma unroll
    for (int kk = 0; kk < 8; kk++)
#pragma unroll
        for (int c = 0; c < 2; c++)
            wf[kk][c] = ((const short8*)w2f)[(kk * 8 + w * 2 + c) * 64 + lane];
    float2 bias = *(const float2*)(b2 + w * 32 + col * 2);

    for (int t = blockIdx.x; t < nTiles; t += nb2) {
        const int n0 = t * 16;
        const int nr = n0 + col;                 // N % 16 == 0
        const float* xrow = x + (long)nr * D;
        floatx4 acc[2];
#pragma unroll
        for (int c = 0; c < 2; c++)
#pragma unroll
            for (int q = 0; q < 4; q++) acc[c][q] = 0.f;
#pragma unroll
        for (int kk = 0; kk < 4; kk++) {
            float4 f0 = *(const float4*)(xrow + kk * 32 + quad * 8);
            float4 f1 = *(const float4*)(xrow + kk * 32 + quad * 8 + 4);
            union { short8 s; unsigned int u[4]; } au;
            asm("v_cvt_pk_bf16_f32 %0, %1, %2" : "=v"(au.u[0]) : "v"(f0.x), "v"(f0.y));
            asm("v_cvt_pk_bf16_f32 %0, %1, %2" : "=v"(au.u[1]) : "v"(f0.z), "v"(f0.w));
            asm("v_cvt_pk_bf16_f32 %0, %1, %2" : "=v"(au.u[2]) : "v"(f1.x), "v"(f1.y));
            asm("v_cvt_pk_bf16_f32 %0, %1, %2" : "=v"(au.u[3]) : "v"(f1.z), "v"(f1.w));
            acc[0] = __builtin_amdgcn_mfma_f32_16x16x32_bf16(au.s, wf[kk][0], acc[0], 0, 0, 0);
            acc[1] = __builtin_amdgcn_mfma_f32_16x16x32_bf16(au.s, wf[kk][1], acc[1], 0, 0, 0);
        }
#pragma unroll
        for (int kk = 4; kk < 8; kk++) {
            short8 a = *(const short8*)(aggb + (long)nr * D + (kk - 4) * 32 + quad * 8);
            acc[0] = __builtin_amdgcn_mfma_f32_16x16x32_bf16(a, wf[kk][0], acc[0], 0, 0, 0);
            acc[1] = __builtin_amdgcn_mfma_f32_16x16x32_bf16(a, wf[kk][1], acc[1], 0, 0, 0);
        }
#pragma unroll
        for (int r = 0; r < 4; r++) {
            int n = n0 + quad * 4 + r;
            long off = (long)n * D + w * 32 + col * 2;
            float2 xr = *(const float2*)(x + off);
            float v0 = fmaxf(acc[0][r] + bias.x, 0.f);
            float v1 = fmaxf(acc[1][r] + bias.y, 0.f);
            *(float2*)(out + off) = make_float2(xr.x + v0, xr.y + v1);
        }
    }
}

extern "C" void kernel_launch(void* const* d_in, const int* in_sizes, int n_in,
                              void* d_out, int out_size, void* d_ws, size_t ws_size,
                              hipStream_t stream)
{
    const float* x   = (const float*)d_in[0];
    const int* esrc  = (const int*)d_in[1];
    const int* edst  = (const int*)d_in[2];
    const float* W1  = (const float*)d_in[3];
    const float* b1  = (const float*)d_in[4];
    const float* W2  = (const float*)d_in[5];
    const float* b2  = (const float*)d_in[6];
    float* out = (float*)d_out;

    const int ND = in_sizes[0];     // N*D
    const int N  = ND / D;          // 50000
    const int E  = in_sizes[1];     // 600000

    // workspace carve-out (256B-aligned chunks), ~42 MB
    char* p = (char*)d_ws;
    auto alloc = [&](size_t bytes) { char* r = p; p += (bytes + 255) & ~(size_t)255; return r; };
    unsigned short* Ys   = (unsigned short*)alloc((size_t)ND * 2);
    unsigned short* Yd   = (unsigned short*)alloc((size_t)ND * 2);
    unsigned short* aggb = (unsigned short*)alloc((size_t)ND * 2);
    unsigned short* w1f  = (unsigned short*)alloc(32768 * 2);
    unsigned short* w2f  = (unsigned short*)alloc(32768 * 2);
    int* rowptr = (int*)alloc((size_t)(N + 1) * 4);
    int* cursor = (int*)alloc((size_t)N * 4);
    int* cnt    = (int*)alloc((size_t)N * 4);
    int* ssrc   = (int*)alloc((size_t)E * 4);

    const int nTiles = N / 16;              // 3125 (N % 16 == 0)
    const int nb1 = (nTiles + 2) / 3;       // 1042: each gemm1 block does <=3 tiles
    const int nbh = 256;                    // histogram blocks appended to D2
    const int nb2 = nb1;

    k_pre<<<256, 256, 0, stream>>>(W1, W2, w1f, w2f, cnt, N);
    k_fat1<<<nb1 + nbh, 256, 0, stream>>>(x, w1f, b1, Ys, Yd, edst, cnt, N, nTiles, nb1, E);
    k_scan<<<1, 1024, 0, stream>>>(cnt, rowptr, cursor, N, E);
    k_scatter<<<((E >> 2) + 255) / 256, 256, 0, stream>>>(esrc, edst, cursor, ssrc, E);
    k_agg<<<(N + 3) / 4, 256, 0, stream>>>(Ys, Yd, rowptr, ssrc, aggb, N);
    k_gemm2<<<nb2, 256, 0, stream>>>(x, aggb, w2f, b2, out, N, nTiles, nb2);
}